// Round 12
// baseline (144.646 us; speedup 1.0000x reference)
//
#include <hip/hip_runtime.h>
#include <stdint.h>

#define E_DIM   1024
#define HNUM    16
#define DH      64
#define BATCH   2
#define SEQ     2048
#define M_TOT   (BATCH*SEQ)   // 4096
#define LOG2E   1.44269504088896340736f

typedef __bf16 bf16x8 __attribute__((ext_vector_type(8)));
typedef __bf16 bf16x4 __attribute__((ext_vector_type(4)));
typedef float  f32x4  __attribute__((ext_vector_type(4)));
typedef float  f32x16 __attribute__((ext_vector_type(16)));
typedef unsigned short u16;
typedef unsigned int   u32;
typedef unsigned long long u64;
typedef u16 u16x8 __attribute__((ext_vector_type(8)));
typedef u32 u32x2 __attribute__((ext_vector_type(2)));
typedef u32 u32x4 __attribute__((ext_vector_type(4)));

__device__ __forceinline__ u16 f2bf(float f) {
    u32 u = __builtin_bit_cast(u32, f);
    u32 r = 0x7FFFu + ((u >> 16) & 1u);
    return (u16)((u + r) >> 16);
}

__device__ __forceinline__ void gload_lds16(const u16* g, u16* l) {
    __builtin_amdgcn_global_load_lds(
        (const __attribute__((address_space(1))) u32*)g,
        (__attribute__((address_space(3))) u32*)l, 16, 0, 0);
}

__device__ __forceinline__ u32 cvt_pk_bf16(float lo, float hi) {
    u32 r;
    asm("v_cvt_pk_bf16_f32 %0, %1, %2" : "=v"(r) : "v"(lo), "v"(hi));
    return r;
}

#define MFMA16(a,b,c) __builtin_amdgcn_mfma_f32_16x16x32_bf16((a),(b),(c),0,0,0)
#define MFMA32(a,b,c) __builtin_amdgcn_mfma_f32_32x32x16_bf16((a),(b),(c),0,0,0)

// ---------------- cast x (fp32 -> bf16) ----------------
__global__ __launch_bounds__(256) void cast_x_kernel(const float* __restrict__ x,
                                                     u16* __restrict__ out, int n) {
    int idx = (blockIdx.x * 256 + threadIdx.x) * 4;
    if (idx < n) {
        float4 v = *reinterpret_cast<const float4*>(x + idx);
        ushort4 o;
        o.x = f2bf(v.x); o.y = f2bf(v.y); o.z = f2bf(v.z); o.w = f2bf(v.w);
        *reinterpret_cast<ushort4*>(out + idx) = o;
    }
}

// ---------------- mask -> 64-bit bitmaps ----------------
__global__ __launch_bounds__(256) void maskbits_kernel(const int* __restrict__ mask,
                                                       u64* __restrict__ bits) {
    int i = blockIdx.x * 256 + threadIdx.x;
    u64 bl = __ballot(mask[i] != 0);
    if ((i & 63) == 0) bits[i >> 6] = bl;
}

// ---------------- weight transpose + cast: Wt[n][k] = bf16(W[k][n]) ----------------
__global__ void wtrans_kernel(const float* __restrict__ w0, const float* __restrict__ w1,
                              const float* __restrict__ w2, const float* __restrict__ w3,
                              u16* __restrict__ out) {
    __shared__ float tile[32][33];
    const float* w = blockIdx.z == 0 ? w0 : blockIdx.z == 1 ? w1 : blockIdx.z == 2 ? w2 : w3;
    const int n0 = blockIdx.x * 32, k0 = blockIdx.y * 32;
    #pragma unroll
    for (int j = 0; j < 4; j++) {
        int k = k0 + threadIdx.y + j * 8;
        tile[threadIdx.y + j * 8][threadIdx.x] = w[(size_t)k * E_DIM + n0 + threadIdx.x];
    }
    __syncthreads();
    u16* o = out + (size_t)blockIdx.z * E_DIM * E_DIM;
    #pragma unroll
    for (int j = 0; j < 4; j++) {
        int n = n0 + threadIdx.y + j * 8;
        o[(size_t)n * E_DIM + k0 + threadIdx.x] = f2bf(tile[threadIdx.x][threadIdx.y + j * 8]);
    }
}

// ---------------- GEMM: C[z] = A @ Wt[z]^T + bias[z], scale on z==0 ----------------
template <typename OutT>
__global__ __launch_bounds__(256) void gemm_kernel(
    const u16* __restrict__ A, const u16* __restrict__ Bt_base, OutT* __restrict__ C_base,
    const float* __restrict__ bias0, const float* __restrict__ bias1,
    const float* __restrict__ bias2, float scale0, int Mdim) {
    const int z = blockIdx.z;
    const u16* Bt = Bt_base + (size_t)z * E_DIM * E_DIM;
    OutT* C = C_base + (size_t)z * Mdim * E_DIM;
    const float* bias = (z == 0) ? bias0 : (z == 1 ? bias1 : bias2);
    const float scale = (z == 0) ? scale0 : 1.0f;

    __shared__ __align__(16) u16 Als[128 * 32];
    __shared__ __align__(16) u16 Bls[128 * 32];

    const int tid = threadIdx.x;
    const int lane = tid & 63;
    const int w = tid >> 6;
    const int wr = (w >> 1) * 64, wc = (w & 1) * 64;
    const int tm = blockIdx.y * 128, tn = blockIdx.x * 128;
    const int r4 = tid >> 2;
    const int c8 = (tid & 3) * 8;

    f32x4 acc[4][4] = {};

    for (int k0 = 0; k0 < E_DIM; k0 += 32) {
        gload_lds16(A + (size_t)(tm + r4) * E_DIM + k0 + c8, Als + tid * 8);
        gload_lds16(A + (size_t)(tm + 64 + r4) * E_DIM + k0 + c8, Als + 2048 + tid * 8);
        gload_lds16(Bt + (size_t)(tn + r4) * E_DIM + k0 + c8, Bls + tid * 8);
        gload_lds16(Bt + (size_t)(tn + 64 + r4) * E_DIM + k0 + c8, Bls + 2048 + tid * 8);
        __syncthreads();
        const int lr = lane & 15, lg = lane >> 4;
        bf16x8 af[4], bfr[4];
        #pragma unroll
        for (int m = 0; m < 4; m++)
            af[m] = *reinterpret_cast<const bf16x8*>(Als + (wr + m * 16 + lr) * 32 + lg * 8);
        #pragma unroll
        for (int n = 0; n < 4; n++)
            bfr[n] = *reinterpret_cast<const bf16x8*>(Bls + (wc + n * 16 + lr) * 32 + lg * 8);
        #pragma unroll
        for (int m = 0; m < 4; m++)
            #pragma unroll
            for (int n = 0; n < 4; n++)
                acc[m][n] = MFMA16(af[m], bfr[n], acc[m][n]);
        __syncthreads();
    }

    const int lr = lane & 15, lg = lane >> 4;
    #pragma unroll
    for (int m = 0; m < 4; m++) {
        #pragma unroll
        for (int n = 0; n < 4; n++) {
            const int col = tn + wc + n * 16 + lr;
            const float bv = bias[col];
            #pragma unroll
            for (int r = 0; r < 4; r++) {
                const int row = tm + wr + m * 16 + lg * 4 + r;
                float v = (acc[m][n][r] + bv) * scale;
                if constexpr (sizeof(OutT) == 2) {
                    C[(size_t)row * E_DIM + col] = f2bf(v);
                } else {
                    C[(size_t)row * E_DIM + col] = v;
                }
            }
        }
    }
}

// ---------------- flash attention: in-wave pipelined, ping-pong score regs ----------------
// 512 blocks (XCD-local 1D: n&31 = (h,b) group -> 4 groups/XCD, K/V 2MB/XCD L2-resident),
// 256 thr (4 waves x 32 q-rows), NT=32 key-tiles. K staged 3 ahead (4-slot LDS ring,
// global_load_lds, per-tile s_waitcnt vmcnt(2) keeps K(t+3) in flight). V reg-staged dbuf
// (issue-early/write-late). Tile t: softmax(s_cur) -> P -> QK(t+1) into the OTHER score
// register pair (ping-pong, no rotate movs) -> PV(t). Fixed-max exp2 softmax; Q pre-scaled
// by (1/sqrt(D))*log2(e); normalized output written directly (no combine pass).
__global__ __launch_bounds__(256) void attn_kernel(
    const u16* __restrict__ Q, const u16* __restrict__ K, const u16* __restrict__ V,
    const u64* __restrict__ mbits, u16* __restrict__ Out) {
    // K slot: [key][d] row-major, byte ^= ((key&7)<<4). Vt slot: [d][key], byte ^= ((d&7)<<4).
    __shared__ __align__(16) u16 Kls[4][64 * 64];   // 32KB ring, slot stride 8192B
    __shared__ __align__(16) u16 Vt[2][64 * 64];    // 16KB dbuf, slot stride 8192B

    const int tid = threadIdx.x;
    const int lane = tid & 63;
    const int w = tid >> 6;
    const int hi = lane >> 5;
    const int l31 = lane & 31;
    const int n = blockIdx.x;
    const int g = n & 31, qt = n >> 5;
    const int h = g & 15, b = g >> 4;

    // Q fragments (B-operand: col=q=lane&31, k-elems d = kc*16 + 8*hi + i)
    const int qrow = b * SEQ + qt * 128 + w * 32 + l31;
    bf16x8 qf[4];
    #pragma unroll
    for (int kc = 0; kc < 4; kc++)
        qf[kc] = *reinterpret_cast<const bf16x8*>(Q + (size_t)qrow * E_DIM + h * DH + kc * 16 + hi * 8);

    // K A-row remap (bits 2<->3) + per-lane K read offsets (loop-invariant)
    const int krow = (l31 & 3) | ((l31 & 4) << 1) | ((l31 & 8) >> 1) | (l31 & 16);
    const u32 ksw = (u32)(krow & 7) << 4;
    u32 koff[4];
    #pragma unroll
    for (int kc = 0; kc < 4; kc++)
        koff[kc] = (((u32)krow * 128) + (u32)kc * 32 + (u32)hi * 16) ^ ksw;

    // K staging (gload_lds, pre-swizzled source chunk)
    const int krA = tid >> 3;
    const int kcA = (tid & 7) ^ (krA & 7);
    const size_t kgoffA = (size_t)krA * E_DIM + kcA * 8;
    const size_t kgoffB = kgoffA + (size_t)32 * E_DIM;

    // V staging roles + loop-invariant LDS offsets
    const int vc = tid & 7;
    const int vsg = ((tid >> 3) ^ (vc << 2)) & 31;
    const size_t vgoff = (size_t)(2 * vsg) * E_DIM + vc * 8;
    u32 vwoff[8];
    #pragma unroll
    for (int j = 0; j < 8; j++)
        vwoff[j] = (((u32)(vc * 8 + j) * 128) + (u32)vsg * 4) ^ ((u32)j << 4);
    u32 vroff[4];
    #pragma unroll
    for (int kc = 0; kc < 4; kc++)
        vroff[kc] = (((u32)l31 * 128) + (u32)(2 * kc + hi) * 16) ^ (((u32)(l31 & 7)) << 4);

    f32x16 oacc0 = {}, oacc1 = {};
    float l_run = 0.f;

    const u16* Kg = K + (size_t)(b * SEQ) * E_DIM + h * DH;
    const u16* Vg = V + (size_t)(b * SEQ) * E_DIM + h * DH;
    const size_t TSTEP = (size_t)64 * E_DIM;
    const u16* kga = Kg + kgoffA;
    const u16* kgb = Kg + kgoffB;
    const u16* vgp = Vg + vgoff;
    const int NT = SEQ / 64;   // 32

    // ---- prologue: V(0) regs, K(0..2) gloads; vmcnt(2); V0 write; barrier ----
    {
        u32x4 a0 = *reinterpret_cast<const u32x4*>(vgp);
        u32x4 a1 = *reinterpret_cast<const u32x4*>(vgp + E_DIM);
        gload_lds16(kga,             &Kls[0][tid * 8]);
        gload_lds16(kgb,             &Kls[0][(tid + 256) * 8]);
        gload_lds16(kga + TSTEP,     &Kls[1][tid * 8]);
        gload_lds16(kgb + TSTEP,     &Kls[1][(tid + 256) * 8]);
        gload_lds16(kga + 2 * TSTEP, &Kls[2][tid * 8]);
        gload_lds16(kgb + 2 * TSTEP, &Kls[2][(tid + 256) * 8]);
        kga += 3 * TSTEP; kgb += 3 * TSTEP; vgp += TSTEP;
        asm volatile("s_waitcnt vmcnt(2)" ::: "memory");   // V0,K0,K1 done; K2 in flight
        __builtin_amdgcn_sched_barrier(0);
        #pragma unroll
        for (int j = 0; j < 8; j++)
            *(u32*)((char*)Vt + vwoff[j]) = __builtin_amdgcn_perm(
                a1[j >> 1], a0[j >> 1], (j & 1) ? 0x07060302u : 0x05040100u);
        asm volatile("s_waitcnt lgkmcnt(0)" ::: "memory");
        __builtin_amdgcn_sched_barrier(0);
        __builtin_amdgcn_s_barrier();
    }

    // ---- sA = QK(0) ----
    f32x16 sA0 = {}, sA1 = {}, sB0 = {}, sB1 = {};
    {
        const char* Kb = (const char*)Kls;   // slot 0
        __builtin_amdgcn_s_setprio(1);
        #pragma unroll
        for (int kc = 0; kc < 4; kc++) {
            bf16x8 kf0 = *(const bf16x8*)(Kb + koff[kc]);
            bf16x8 kf1 = *(const bf16x8*)(Kb + koff[kc] + 4096);
            sA0 = MFMA32(kf0, qf[kc], sA0);
            sA1 = MFMA32(kf1, qf[kc], sA1);
        }
        __builtin_amdgcn_s_setprio(0);
    }

    // tile body: softmax+PV on (c0,c1) for tile t; QK(t+1) into (n0,n1)
    auto tile_body = [&](f32x16& c0, f32x16& c1, f32x16& n0, f32x16& n1, int t) {
        const bool haveV = (t + 1 < NT);
        const bool haveK = (t + 3 < NT);
        u32x4 a0, a1;
        if (haveV) {   // V(t+1) regs FIRST (covered by vmcnt(2))
            a0 = *reinterpret_cast<const u32x4*>(vgp);
            a1 = *reinterpret_cast<const u32x4*>(vgp + E_DIM);
        }
        if (haveK) {   // K(t+3) gloads (stay in flight across barrier)
            gload_lds16(kga, &Kls[(t + 3) & 3][tid * 8]);
            gload_lds16(kgb, &Kls[(t + 3) & 3][(tid + 256) * 8]);
        }

        // softmax (fixed-max exp2), lane-local partial sum
        const u64 mb = mbits[b * NT + t];
        if (mb != ~0ull) {
            #pragma unroll
            for (int r = 0; r < 16; r++) {
                const int key = (r & 3) + 4 * ((r >> 2) & 1) + 8 * hi + 16 * ((r >> 3) & 1);
                if (!((mb >> key) & 1))        c0[r] += -1.442695e9f;
                if (!((mb >> (32 + key)) & 1)) c1[r] += -1.442695e9f;
            }
        }
        float sum = 0.f;
        #pragma unroll
        for (int r = 0; r < 16; r++) { c0[r] = __builtin_amdgcn_exp2f(c0[r]); sum += c0[r]; }
        #pragma unroll
        for (int r = 0; r < 16; r++) { c1[r] = __builtin_amdgcn_exp2f(c1[r]); sum += c1[r]; }
        l_run += sum;

        // P frags via packed cvt
        bf16x8 pf[4];
        {
            u32x4 pw0, pw1, pw2, pw3;
            #pragma unroll
            for (int e = 0; e < 4; e++) {
                pw0[e] = cvt_pk_bf16(c0[2 * e],     c0[2 * e + 1]);
                pw1[e] = cvt_pk_bf16(c0[8 + 2 * e], c0[9 + 2 * e]);
                pw2[e] = cvt_pk_bf16(c1[2 * e],     c1[2 * e + 1]);
                pw3[e] = cvt_pk_bf16(c1[8 + 2 * e], c1[9 + 2 * e]);
            }
            pf[0] = __builtin_bit_cast(bf16x8, pw0);
            pf[1] = __builtin_bit_cast(bf16x8, pw1);
            pf[2] = __builtin_bit_cast(bf16x8, pw2);
            pf[3] = __builtin_bit_cast(bf16x8, pw3);
        }

        // QK(t+1) into the other score pair (independent MFMA stream)
        n0 = f32x16{};
        n1 = f32x16{};
        if (haveV) {
            const char* Kb = (const char*)Kls + ((t + 1) & 3) * 8192;
            __builtin_amdgcn_s_setprio(1);
            #pragma unroll
            for (int kc = 0; kc < 4; kc++) {
                bf16x8 kf0 = *(const bf16x8*)(Kb + koff[kc]);
                bf16x8 kf1 = *(const bf16x8*)(Kb + koff[kc] + 4096);
                n0 = MFMA32(kf0, qf[kc], n0);
                n1 = MFMA32(kf1, qf[kc], n1);
            }
            __builtin_amdgcn_s_setprio(0);
        }

        // PV(t)
        {
            const char* Vb = (const char*)Vt + (t & 1) * 8192;
            __builtin_amdgcn_s_setprio(1);
            #pragma unroll
            for (int kc = 0; kc < 4; kc++) {
                bf16x8 vf0 = *(const bf16x8*)(Vb + vroff[kc]);
                bf16x8 vf1 = *(const bf16x8*)(Vb + vroff[kc] + 4096);
                oacc0 = MFMA32(vf0, pf[kc], oacc0);
                oacc1 = MFMA32(vf1, pf[kc], oacc1);
            }
            __builtin_amdgcn_s_setprio(0);
        }

        // counted vmcnt: K(t+2),V(t+1) complete; K(t+3) stays in flight
        asm volatile("s_waitcnt vmcnt(2)" ::: "memory");
        __builtin_amdgcn_sched_barrier(0);
        if (haveV) {
            #pragma unroll
            for (int j = 0; j < 8; j++)
                *(u32*)((char*)Vt + ((t + 1) & 1) * 8192 + vwoff[j]) = __builtin_amdgcn_perm(
                    a1[j >> 1], a0[j >> 1], (j & 1) ? 0x07060302u : 0x05040100u);
        }
        asm volatile("s_waitcnt lgkmcnt(0)" ::: "memory");
        __builtin_amdgcn_sched_barrier(0);
        __builtin_amdgcn_s_barrier();

        if (haveK) { kga += TSTEP; kgb += TSTEP; }
        if (haveV) { vgp += TSTEP; }
    };

    // ping-pong pairs: no score-register rotation
    for (int tp = 0; tp < NT / 2; tp++) {
        tile_body(sA0, sA1, sB0, sB1, 2 * tp);
        tile_body(sB0, sB1, sA0, sA1, 2 * tp + 1);
    }

    // ---- epilogue: combine key-halves of l, normalize, store bf16 ----
    const float l_tot = l_run + __shfl_xor(l_run, 32);
    const float rl = 1.0f / l_tot;
    u16* op = Out + (size_t)qrow * E_DIM + h * DH;
    #pragma unroll
    for (int db = 0; db < 2; db++) {
        #pragma unroll
        for (int j = 0; j < 4; j++) {
            u32x2 pk;
            pk[0] = cvt_pk_bf16((db ? oacc1[4 * j + 0] : oacc0[4 * j + 0]) * rl,
                                (db ? oacc1[4 * j + 1] : oacc0[4 * j + 1]) * rl);
            pk[1] = cvt_pk_bf16((db ? oacc1[4 * j + 2] : oacc0[4 * j + 2]) * rl,
                                (db ? oacc1[4 * j + 3] : oacc0[4 * j + 3]) * rl);
            const int d0 = 32 * db + 8 * j + 4 * hi;
            *reinterpret_cast<u32x2*>(op + d0) = pk;
        }
    }
}

extern "C" void kernel_launch(void* const* d_in, const int* in_sizes, int n_in,
                              void* d_out, int out_size, void* d_ws, size_t ws_size,
                              hipStream_t stream) {
    const float* x  = (const float*)d_in[0];
    const int* mask = (const int*)d_in[1];
    const float* Wq = (const float*)d_in[2];
    const float* bq = (const float*)d_in[3];
    const float* Wk = (const float*)d_in[4];
    const float* bk = (const float*)d_in[5];
    const float* Wv = (const float*)d_in[6];
    const float* bv = (const float*)d_in[7];
    const float* Wo = (const float*)d_in[8];
    const float* bo = (const float*)d_in[9];
    float* out = (float*)d_out;

    u16* ws  = (u16*)d_ws;
    const size_t ME = (size_t)M_TOT * E_DIM;         // 4194304
    u16* xb  = ws;                                   // [M][E] bf16 x ; later reused as ab
    u16* wt  = ws + ME;                              // 4x [E][E] bf16 W^T (q,k,v,o)
    u16* qb  = ws + 2 * ME;                          // Q,K,V contiguous [3][M][E]
    u16* kbf = ws + 3 * ME;
    u16* vbf = ws + 4 * ME;
    u64* mbf = (u64*)(ws + 5 * ME);                  // 64 u64 mask bitmaps (512B)
    u16* ab  = xb;                                   // attn concat aliases xb (dead after QKV gemm)

    cast_x_kernel<<<dim3(M_TOT * E_DIM / 1024), dim3(256), 0, stream>>>(x, xb, M_TOT * E_DIM);
    wtrans_kernel<<<dim3(E_DIM / 32, E_DIM / 32, 4), dim3(32, 8), 0, stream>>>(Wq, Wk, Wv, Wo, wt);
    maskbits_kernel<<<dim3(M_TOT / 256), dim3(256), 0, stream>>>(mask, mbf);
    gemm_kernel<u16><<<dim3(E_DIM / 128, M_TOT / 128, 3), dim3(256), 0, stream>>>(
        xb, wt, qb, bq, bk, bv, 0.125f * LOG2E, M_TOT);
    attn_kernel<<<dim3(512), dim3(256), 0, stream>>>(qb, kbf, vbf, mbf, ab);
    gemm_kernel<float><<<dim3(E_DIM / 128, M_TOT / 128, 1), dim3(256), 0, stream>>>(
        ab, wt + (size_t)3 * E_DIM * E_DIM, out, bo, bo, bo, 1.0f, M_TOT);
}

// Round 13
// 128.811 us; speedup vs baseline: 1.1229x; 1.1229x over previous
//
#include <hip/hip_runtime.h>
#include <stdint.h>

#define E_DIM   1024
#define HNUM    16
#define DH      64
#define BATCH   2
#define SEQ     2048
#define M_TOT   (BATCH*SEQ)   // 4096
#define LOG2E   1.44269504088896340736f

typedef __bf16 bf16x8 __attribute__((ext_vector_type(8)));
typedef __bf16 bf16x4 __attribute__((ext_vector_type(4)));
typedef float  f32x4  __attribute__((ext_vector_type(4)));
typedef float  f32x16 __attribute__((ext_vector_type(16)));
typedef unsigned short u16;
typedef unsigned int   u32;
typedef unsigned long long u64;
typedef u16 u16x8 __attribute__((ext_vector_type(8)));
typedef u32 u32x2 __attribute__((ext_vector_type(2)));
typedef u32 u32x4 __attribute__((ext_vector_type(4)));

__device__ __forceinline__ u16 f2bf(float f) {
    u32 u = __builtin_bit_cast(u32, f);
    u32 r = 0x7FFFu + ((u >> 16) & 1u);
    return (u16)((u + r) >> 16);
}

__device__ __forceinline__ void gload_lds16(const u16* g, u16* l) {
    __builtin_amdgcn_global_load_lds(
        (const __attribute__((address_space(1))) u32*)g,
        (__attribute__((address_space(3))) u32*)l, 16, 0, 0);
}

__device__ __forceinline__ u32 cvt_pk_bf16(float lo, float hi) {
    u32 r;
    asm("v_cvt_pk_bf16_f32 %0, %1, %2" : "=v"(r) : "v"(lo), "v"(hi));
    return r;
}

#define MFMA16(a,b,c) __builtin_amdgcn_mfma_f32_16x16x32_bf16((a),(b),(c),0,0,0)
#define MFMA32(a,b,c) __builtin_amdgcn_mfma_f32_32x32x16_bf16((a),(b),(c),0,0,0)

// ---------------- cast x (fp32 -> bf16) ----------------
__global__ __launch_bounds__(256) void cast_x_kernel(const float* __restrict__ x,
                                                     u16* __restrict__ out, int n) {
    int idx = (blockIdx.x * 256 + threadIdx.x) * 4;
    if (idx < n) {
        float4 v = *reinterpret_cast<const float4*>(x + idx);
        ushort4 o;
        o.x = f2bf(v.x); o.y = f2bf(v.y); o.z = f2bf(v.z); o.w = f2bf(v.w);
        *reinterpret_cast<ushort4*>(out + idx) = o;
    }
}

// ---------------- mask -> 64-bit bitmaps ----------------
__global__ __launch_bounds__(256) void maskbits_kernel(const int* __restrict__ mask,
                                                       u64* __restrict__ bits) {
    int i = blockIdx.x * 256 + threadIdx.x;
    u64 bl = __ballot(mask[i] != 0);
    if ((i & 63) == 0) bits[i >> 6] = bl;
}

// ---------------- weight transpose + cast: Wt[n][k] = bf16(W[k][n]) ----------------
__global__ void wtrans_kernel(const float* __restrict__ w0, const float* __restrict__ w1,
                              const float* __restrict__ w2, const float* __restrict__ w3,
                              u16* __restrict__ out) {
    __shared__ float tile[32][33];
    const float* w = blockIdx.z == 0 ? w0 : blockIdx.z == 1 ? w1 : blockIdx.z == 2 ? w2 : w3;
    const int n0 = blockIdx.x * 32, k0 = blockIdx.y * 32;
    #pragma unroll
    for (int j = 0; j < 4; j++) {
        int k = k0 + threadIdx.y + j * 8;
        tile[threadIdx.y + j * 8][threadIdx.x] = w[(size_t)k * E_DIM + n0 + threadIdx.x];
    }
    __syncthreads();
    u16* o = out + (size_t)blockIdx.z * E_DIM * E_DIM;
    #pragma unroll
    for (int j = 0; j < 4; j++) {
        int n = n0 + threadIdx.y + j * 8;
        o[(size_t)n * E_DIM + k0 + threadIdx.x] = f2bf(tile[threadIdx.x][threadIdx.y + j * 8]);
    }
}

// ---------------- GEMM: C[z] = A @ Wt[z]^T + bias[z], scale on z==0 ----------------
template <typename OutT>
__global__ __launch_bounds__(256) void gemm_kernel(
    const u16* __restrict__ A, const u16* __restrict__ Bt_base, OutT* __restrict__ C_base,
    const float* __restrict__ bias0, const float* __restrict__ bias1,
    const float* __restrict__ bias2, float scale0, int Mdim) {
    const int z = blockIdx.z;
    const u16* Bt = Bt_base + (size_t)z * E_DIM * E_DIM;
    OutT* C = C_base + (size_t)z * Mdim * E_DIM;
    const float* bias = (z == 0) ? bias0 : (z == 1 ? bias1 : bias2);
    const float scale = (z == 0) ? scale0 : 1.0f;

    __shared__ __align__(16) u16 Als[128 * 32];
    __shared__ __align__(16) u16 Bls[128 * 32];

    const int tid = threadIdx.x;
    const int lane = tid & 63;
    const int w = tid >> 6;
    const int wr = (w >> 1) * 64, wc = (w & 1) * 64;
    const int tm = blockIdx.y * 128, tn = blockIdx.x * 128;
    const int r4 = tid >> 2;
    const int c8 = (tid & 3) * 8;

    f32x4 acc[4][4] = {};

    for (int k0 = 0; k0 < E_DIM; k0 += 32) {
        gload_lds16(A + (size_t)(tm + r4) * E_DIM + k0 + c8, Als + tid * 8);
        gload_lds16(A + (size_t)(tm + 64 + r4) * E_DIM + k0 + c8, Als + 2048 + tid * 8);
        gload_lds16(Bt + (size_t)(tn + r4) * E_DIM + k0 + c8, Bls + tid * 8);
        gload_lds16(Bt + (size_t)(tn + 64 + r4) * E_DIM + k0 + c8, Bls + 2048 + tid * 8);
        __syncthreads();
        const int lr = lane & 15, lg = lane >> 4;
        bf16x8 af[4], bfr[4];
        #pragma unroll
        for (int m = 0; m < 4; m++)
            af[m] = *reinterpret_cast<const bf16x8*>(Als + (wr + m * 16 + lr) * 32 + lg * 8);
        #pragma unroll
        for (int n = 0; n < 4; n++)
            bfr[n] = *reinterpret_cast<const bf16x8*>(Bls + (wc + n * 16 + lr) * 32 + lg * 8);
        #pragma unroll
        for (int m = 0; m < 4; m++)
            #pragma unroll
            for (int n = 0; n < 4; n++)
                acc[m][n] = MFMA16(af[m], bfr[n], acc[m][n]);
        __syncthreads();
    }

    const int lr = lane & 15, lg = lane >> 4;
    #pragma unroll
    for (int m = 0; m < 4; m++) {
        #pragma unroll
        for (int n = 0; n < 4; n++) {
            const int col = tn + wc + n * 16 + lr;
            const float bv = bias[col];
            #pragma unroll
            for (int r = 0; r < 4; r++) {
                const int row = tm + wr + m * 16 + lg * 4 + r;
                float v = (acc[m][n][r] + bv) * scale;
                if constexpr (sizeof(OutT) == 2) {
                    C[(size_t)row * E_DIM + col] = f2bf(v);
                } else {
                    C[(size_t)row * E_DIM + col] = v;
                }
            }
        }
    }
}

// ---------------- flash attention: R11 pipeline, 2 q-tiles/block (512 thr) ----------------
// 512 blocks (XCD-local 1D: n&63 = (h,b,half) group, n>>6 = q-block of 256 rows).
// Waves 0-3 -> q-rows [0,128), waves 4-7 -> [128,256) of the q-block; ONE shared K/V
// stream per block (K/V staging traffic halved vs R11). K: 4-slot LDS ring staged 3
// ahead via ONE gload_lds per thread (512 thr cover 64x64 tile); per-tile
// s_waitcnt vmcnt(1) keeps K(t+3) in flight. V: reg-staged dbuf, 512 threads each
// read 2x u32x2 and write 4 u32 (issue-early/write-late). Per-wave compute identical
// to R11: softmax(s_cur) -> P -> QK(t+1) -> PV(t) -> rotate. Fixed-max exp2 softmax;
// key-split partials; Q pre-scaled by (1/sqrt(D))*log2(e).
__global__ __launch_bounds__(512) void attn_kernel(
    const u16* __restrict__ Q, const u16* __restrict__ K, const u16* __restrict__ V,
    const u64* __restrict__ mbits, u16* __restrict__ PO, float* __restrict__ lws) {
    // K slot: [key][d] row-major, byte ^= ((key&7)<<4). Vt slot: [d][key], byte ^= ((d&7)<<4).
    __shared__ __align__(16) u16 Kls[4][64 * 64];   // 32KB ring, slot stride 8192B
    __shared__ __align__(16) u16 Vt[2][64 * 64];    // 16KB dbuf, slot stride 8192B

    const int tid = threadIdx.x;          // 0..511
    const int lane = tid & 63;
    const int wave = tid >> 6;            // 0..7
    const int sub = wave >> 2;            // q-sub-tile (0/1)
    const int wg = wave & 3;              // wave within sub-tile
    const int hi = lane >> 5;
    const int l31 = lane & 31;
    const int n = blockIdx.x;
    const int g = n & 63, qt = n >> 6;    // qt in 0..7 (256 q-rows each)
    const int h = g & 15, zz = g >> 4;
    const int b = zz >> 1, half = zz & 1;

    // Q fragments (B-operand: col=q=lane&31, k-elems d = kc*16 + 8*hi + i)
    const int qrow = b * SEQ + qt * 256 + sub * 128 + wg * 32 + l31;
    bf16x8 qf[4];
    #pragma unroll
    for (int kc = 0; kc < 4; kc++)
        qf[kc] = *reinterpret_cast<const bf16x8*>(Q + (size_t)qrow * E_DIM + h * DH + kc * 16 + hi * 8);

    // K A-row remap (bits 2<->3) + per-lane K read offsets (loop-invariant)
    const int krow = (l31 & 3) | ((l31 & 4) << 1) | ((l31 & 8) >> 1) | (l31 & 16);
    const u32 ksw = (u32)(krow & 7) << 4;
    u32 koff[4];
    #pragma unroll
    for (int kc = 0; kc < 4; kc++)
        koff[kc] = (((u32)krow * 128) + (u32)kc * 32 + (u32)hi * 16) ^ ksw;

    // K staging: 512 threads cover the 64x64 tile with ONE gload_lds each
    const int krA = tid >> 3;                         // row 0..63
    const int kcA = (tid & 7) ^ (krA & 7);            // pre-swizzled source chunk
    const size_t kgoff = (size_t)krA * E_DIM + kcA * 8;

    // V staging: role t8 = tid&255 (chunk vc, row-pair vs); vhalf picks 4 of the 8 j's
    const int t8 = tid & 255;
    const int vhalf = tid >> 8;
    const int vc = t8 & 7;
    const int vsg = ((t8 >> 3) ^ (vc << 2)) & 31;
    const size_t vgoff = (size_t)(2 * vsg) * E_DIM + vc * 8 + vhalf * 4;
    u32 vwoff[4];
    #pragma unroll
    for (int jj = 0; jj < 4; jj++) {
        const int j = vhalf * 4 + jj;
        vwoff[jj] = (((u32)(vc * 8 + j) * 128) + (u32)vsg * 4) ^ ((u32)j << 4);
    }
    u32 vroff[4];
    #pragma unroll
    for (int kc = 0; kc < 4; kc++)
        vroff[kc] = (((u32)l31 * 128) + (u32)(2 * kc + hi) * 16) ^ (((u32)(l31 & 7)) << 4);

    f32x16 oacc0 = {}, oacc1 = {};
    float l_run = 0.f;

    const u16* Kg = K + (size_t)(b * SEQ + half * (SEQ / 2)) * E_DIM + h * DH;
    const u16* Vg = V + (size_t)(b * SEQ + half * (SEQ / 2)) * E_DIM + h * DH;
    const size_t TSTEP = (size_t)64 * E_DIM;
    const u16* kgp = Kg + kgoff;
    const u16* vgp = Vg + vgoff;
    const int NT = SEQ / 2 / 64;   // 16

    // ---- prologue: V(0) regs, K(0..2) gloads; vmcnt(1); V0 write; barrier ----
    {
        u32x2 a0 = *reinterpret_cast<const u32x2*>(vgp);
        u32x2 a1 = *reinterpret_cast<const u32x2*>(vgp + E_DIM);
        gload_lds16(kgp,             &Kls[0][tid * 8]);
        gload_lds16(kgp + TSTEP,     &Kls[1][tid * 8]);
        gload_lds16(kgp + 2 * TSTEP, &Kls[2][tid * 8]);
        kgp += 3 * TSTEP; vgp += TSTEP;
        asm volatile("s_waitcnt vmcnt(1)" ::: "memory");   // V0,K0,K1 done; K2 in flight
        __builtin_amdgcn_sched_barrier(0);
        #pragma unroll
        for (int jj = 0; jj < 4; jj++)
            *(u32*)((char*)Vt + vwoff[jj]) = __builtin_amdgcn_perm(
                a1[jj >> 1], a0[jj >> 1], (jj & 1) ? 0x07060302u : 0x05040100u);
        asm volatile("s_waitcnt lgkmcnt(0)" ::: "memory");
        __builtin_amdgcn_sched_barrier(0);
        __builtin_amdgcn_s_barrier();
    }

    // ---- s_cur = QK(0) ----
    f32x16 sc0 = {}, sc1 = {};
    {
        const char* Kb = (const char*)Kls;   // slot 0
        __builtin_amdgcn_s_setprio(1);
        #pragma unroll
        for (int kc = 0; kc < 4; kc++) {
            bf16x8 kf0 = *(const bf16x8*)(Kb + koff[kc]);
            bf16x8 kf1 = *(const bf16x8*)(Kb + koff[kc] + 4096);
            sc0 = MFMA32(kf0, qf[kc], sc0);
            sc1 = MFMA32(kf1, qf[kc], sc1);
        }
        __builtin_amdgcn_s_setprio(0);
    }

    for (int t = 0; t < NT; t++) {
        const bool haveV = (t + 1 < NT);
        const bool haveK = (t + 3 < NT);
        u32x2 a0, a1;
        if (haveV) {   // V(t+1) regs FIRST (covered by vmcnt(1) + compiler dep-waits)
            a0 = *reinterpret_cast<const u32x2*>(vgp);
            a1 = *reinterpret_cast<const u32x2*>(vgp + E_DIM);
        }
        if (haveK) {   // K(t+3) gload (stays in flight across barrier)
            gload_lds16(kgp, &Kls[(t + 3) & 3][tid * 8]);
        }

        // ---- softmax on s_cur (tile t): fixed-max exp2, lane-local partial sum ----
        const u64 mb = mbits[b * (SEQ / 64) + half * NT + t];
        if (mb != ~0ull) {
            #pragma unroll
            for (int r = 0; r < 16; r++) {
                const int key = (r & 3) + 4 * ((r >> 2) & 1) + 8 * hi + 16 * ((r >> 3) & 1);
                if (!((mb >> key) & 1))        sc0[r] += -1.442695e9f;
                if (!((mb >> (32 + key)) & 1)) sc1[r] += -1.442695e9f;
            }
        }
        float sum = 0.f;
        #pragma unroll
        for (int r = 0; r < 16; r++) {
            sc0[r] = __builtin_amdgcn_exp2f(sc0[r]); sum += sc0[r];
        }
        #pragma unroll
        for (int r = 0; r < 16; r++) {
            sc1[r] = __builtin_amdgcn_exp2f(sc1[r]); sum += sc1[r];
        }
        l_run += sum;

        // ---- P frags via packed cvt ----
        bf16x8 pf[4];
        {
            u32x4 pw0, pw1, pw2, pw3;
            #pragma unroll
            for (int e = 0; e < 4; e++) {
                pw0[e] = cvt_pk_bf16(sc0[2 * e],     sc0[2 * e + 1]);
                pw1[e] = cvt_pk_bf16(sc0[8 + 2 * e], sc0[9 + 2 * e]);
                pw2[e] = cvt_pk_bf16(sc1[2 * e],     sc1[2 * e + 1]);
                pw3[e] = cvt_pk_bf16(sc1[8 + 2 * e], sc1[9 + 2 * e]);
            }
            pf[0] = __builtin_bit_cast(bf16x8, pw0);
            pf[1] = __builtin_bit_cast(bf16x8, pw1);
            pf[2] = __builtin_bit_cast(bf16x8, pw2);
            pf[3] = __builtin_bit_cast(bf16x8, pw3);
        }

        // ---- s_next = QK(t+1): independent MFMA stream (overlaps softmax above) ----
        f32x16 sn0 = {}, sn1 = {};
        if (haveV) {
            const char* Kb = (const char*)Kls + ((t + 1) & 3) * 8192;
            __builtin_amdgcn_s_setprio(1);
            #pragma unroll
            for (int kc = 0; kc < 4; kc++) {
                bf16x8 kf0 = *(const bf16x8*)(Kb + koff[kc]);
                bf16x8 kf1 = *(const bf16x8*)(Kb + koff[kc] + 4096);
                sn0 = MFMA32(kf0, qf[kc], sn0);
                sn1 = MFMA32(kf1, qf[kc], sn1);
            }
            __builtin_amdgcn_s_setprio(0);
        }

        // ---- PV(t) ----
        {
            const char* Vb = (const char*)Vt + (t & 1) * 8192;
            __builtin_amdgcn_s_setprio(1);
            #pragma unroll
            for (int kc = 0; kc < 4; kc++) {
                bf16x8 vf0 = *(const bf16x8*)(Vb + vroff[kc]);
                bf16x8 vf1 = *(const bf16x8*)(Vb + vroff[kc] + 4096);
                oacc0 = MFMA32(vf0, pf[kc], oacc0);
                oacc1 = MFMA32(vf1, pf[kc], oacc1);
            }
            __builtin_amdgcn_s_setprio(0);
        }

        // ---- counted vmcnt: K(t+2),V(t+1) complete; K(t+3) stays in flight ----
        asm volatile("s_waitcnt vmcnt(1)" ::: "memory");
        __builtin_amdgcn_sched_barrier(0);
        if (haveV) {
            #pragma unroll
            for (int jj = 0; jj < 4; jj++)
                *(u32*)((char*)Vt + ((t + 1) & 1) * 8192 + vwoff[jj]) = __builtin_amdgcn_perm(
                    a1[jj >> 1], a0[jj >> 1], (jj & 1) ? 0x07060302u : 0x05040100u);
        }
        asm volatile("s_waitcnt lgkmcnt(0)" ::: "memory");
        __builtin_amdgcn_sched_barrier(0);
        __builtin_amdgcn_s_barrier();

        sc0 = sn0; sc1 = sn1;
        if (haveK) { kgp += TSTEP; }
        if (haveV) { vgp += TSTEP; }
    }

    // ---- epilogue: combine key-halves of l within wave, store UNNORMALIZED partials ----
    const float l_tot = l_run + __shfl_xor(l_run, 32);
    u16* op = PO + ((size_t)half * M_TOT + qrow) * E_DIM + h * DH;
    #pragma unroll
    for (int db = 0; db < 2; db++) {
        #pragma unroll
        for (int j = 0; j < 4; j++) {
            u32x2 pk;
            pk[0] = cvt_pk_bf16(db ? oacc1[4 * j + 0] : oacc0[4 * j + 0],
                                db ? oacc1[4 * j + 1] : oacc0[4 * j + 1]);
            pk[1] = cvt_pk_bf16(db ? oacc1[4 * j + 2] : oacc0[4 * j + 2],
                                db ? oacc1[4 * j + 3] : oacc0[4 * j + 3]);
            const int d0 = 32 * db + 8 * j + 4 * hi;
            *reinterpret_cast<u32x2*>(op + d0) = pk;
        }
    }
    if (hi == 0) lws[((size_t)half * M_TOT + qrow) * HNUM + h] = l_tot;
}

// ---------------- combine partials: ab = (PO0 + PO1) / (l0 + l1) ----------------
__global__ __launch_bounds__(256) void combine_kernel(const u16* __restrict__ PO,
                                                      const float* __restrict__ lws,
                                                      u16* __restrict__ ab) {
    const int i = (blockIdx.x * 256 + threadIdx.x) * 8;   // elem index in [0, M*E)
    const int row = i >> 10;
    const int h = (i & 1023) >> 6;
    const float l0 = lws[(size_t)row * HNUM + h];
    const float l1 = lws[((size_t)M_TOT + row) * HNUM + h];
    const float rl = 1.0f / (l0 + l1);
    const bf16x8 a = *reinterpret_cast<const bf16x8*>(PO + i);
    const bf16x8 c = *reinterpret_cast<const bf16x8*>(PO + (size_t)M_TOT * E_DIM + i);
    u16x8 o;
    #pragma unroll
    for (int j = 0; j < 8; j++)
        o[j] = f2bf(((float)a[j] + (float)c[j]) * rl);
    *reinterpret_cast<u16x8*>(ab + i) = o;
}

extern "C" void kernel_launch(void* const* d_in, const int* in_sizes, int n_in,
                              void* d_out, int out_size, void* d_ws, size_t ws_size,
                              hipStream_t stream) {
    const float* x  = (const float*)d_in[0];
    const int* mask = (const int*)d_in[1];
    const float* Wq = (const float*)d_in[2];
    const float* bq = (const float*)d_in[3];
    const float* Wk = (const float*)d_in[4];
    const float* bk = (const float*)d_in[5];
    const float* Wv = (const float*)d_in[6];
    const float* bv = (const float*)d_in[7];
    const float* Wo = (const float*)d_in[8];
    const float* bo = (const float*)d_in[9];
    float* out = (float*)d_out;

    u16* ws  = (u16*)d_ws;
    const size_t ME = (size_t)M_TOT * E_DIM;         // 4194304
    u16* xb  = ws;                                   // [M][E] bf16 x ; later reused as ab
    u16* wt  = ws + ME;                              // 4x [E][E] bf16 W^T (q,k,v,o)
    u16* qb  = ws + 2 * ME;                          // Q,K,V contiguous [3][M][E]
    u16* kbf = ws + 3 * ME;
    u16* vbf = ws + 4 * ME;
    u64* mbf = (u64*)(ws + 5 * ME);                  // 64 u64 mask bitmaps (512B)
    float* lws = (float*)(ws + 5 * ME + 8192);       // [2][M][H] f32 l-partials (512KB)
    u16* ab  = xb;                                   // attn concat aliases xb
    u16* po  = (u16*)d_out;                          // partial O scratch: 2x[M][E] bf16 = 16MB

    cast_x_kernel<<<dim3(M_TOT * E_DIM / 1024), dim3(256), 0, stream>>>(x, xb, M_TOT * E_DIM);
    wtrans_kernel<<<dim3(E_DIM / 32, E_DIM / 32, 4), dim3(32, 8), 0, stream>>>(Wq, Wk, Wv, Wo, wt);
    maskbits_kernel<<<dim3(M_TOT / 256), dim3(256), 0, stream>>>(mask, mbf);
    gemm_kernel<u16><<<dim3(E_DIM / 128, M_TOT / 128, 3), dim3(256), 0, stream>>>(
        xb, wt, qb, bq, bk, bv, 0.125f * LOG2E, M_TOT);
    attn_kernel<<<dim3(512), dim3(512), 0, stream>>>(qb, kbf, vbf, mbf, po, lws);
    combine_kernel<<<dim3(M_TOT * E_DIM / 2048), dim3(256), 0, stream>>>(po, lws, ab);
    gemm_kernel<float><<<dim3(E_DIM / 128, M_TOT / 128, 1), dim3(256), 0, stream>>>(
        ab, wt + (size_t)3 * E_DIM * E_DIM, out, bo, bo, bo, 1.0f, M_TOT);
}